// Round 7
// baseline (23.157 us; speedup 1.0000x reference)
//
#include <hip/hip_runtime.h>
#include <stdint.h>

#define BATCH 32
#define NH 12
#define SEQ 785
#define PN 784        // patch_num
#define HDIM 28       // 28*28 == 784
#define VOTE 24       // VOTE_PERHEAD
#define NCHUNK 13     // ceil(784/64)
#define NBIN 128

// Monotonic float -> uint32: k(a) > k(b) iff a > b (finite floats).
__device__ __forceinline__ uint32_t mono_key(float f) {
    uint32_t u = __float_as_uint(f);
    return (u & 0x80000000u) ? ~u : (u | 0x80000000u);
}

// Wave-parallel radix top-r select over 32-bit VALUE keys (desc); ties broken
// by ascending element index (element (c,lane) has index c*64+lane).
// key[c] valid iff bit c of `alive`. Calls win(c) exactly r times.
// 7-bit digits from SHIFT0 down to 0; if keys still tie after the last pass
// (only possible when the unexamined low bits are equal), ballot rank-select
// by index resolves the remainder.
template <int SHIFT0, typename WinF>
__device__ __forceinline__ void wave_select(const uint32_t* key, uint32_t alive,
                                            uint32_t r, uint32_t* histRow,
                                            int lane, WinF&& win) {
    static_assert(SHIFT0 % 7 == 0, "SHIFT0 must be a multiple of 7");
    constexpr int NPASS = SHIFT0 / 7 + 1;
    #pragma unroll 1
    for (int p = 0; p < NPASS; ++p) {
        const int shift = SHIFT0 - 7 * p;
        histRow[2 * lane]     = 0;
        histRow[2 * lane + 1] = 0;
        __threadfence_block();
        #pragma unroll
        for (int c = 0; c < NCHUNK; ++c)
            if (alive & (1u << c))
                atomicAdd(&histRow[(key[c] >> shift) & (NBIN - 1)], 1u);
        __threadfence_block();
        uint32_t h0 = histRow[2 * lane];
        uint32_t h1 = histRow[2 * lane + 1];
        uint32_t x = h0 + h1;
        #pragma unroll
        for (int off = 1; off < 64; off <<= 1) {
            uint32_t t = __shfl_down(x, off, 64);
            if (lane + off < 64) x += t;
        }
        uint32_t tail = x - h0 - h1;          // count of digits >= 2*lane+2
        uint32_t Bc = 0, rc = 0, cc = 0;
        int found = 0;
        if (tail < r && r <= tail + h1) {
            Bc = 2 * lane + 1; rc = r - tail; cc = h1; found = 1;
        } else if (tail + h1 < r && r <= tail + h1 + h0) {
            Bc = 2 * lane; rc = r - tail - h1; cc = h0; found = 1;
        }
        uint64_t fm = __ballot(found);         // exactly one lane sets found
        int src = (int)(__ffsll((unsigned long long)fm) - 1);
        uint32_t B    = __shfl(Bc, src, 64);
        uint32_t rnew = __shfl(rc, src, 64);
        uint32_t cb   = __shfl(cc, src, 64);
        #pragma unroll
        for (int c = 0; c < NCHUNK; ++c) {
            if (alive & (1u << c)) {
                uint32_t bin = (key[c] >> shift) & (NBIN - 1);
                if (bin > B)      { win(c); alive &= ~(1u << c); }
                else if (bin < B) { alive &= ~(1u << c); }
            }
        }
        r = rnew;
        if (cb == rnew) {                      // threshold bin fully wins
            #pragma unroll
            for (int c = 0; c < NCHUNK; ++c)
                if (alive & (1u << c)) win(c);
            return;
        }
    }
    // Exact-key tie: take the r smallest indices among alive.
    uint32_t rem = r;
    #pragma unroll 1
    for (int c = 0; c < NCHUNK && rem; ++c) {
        int pred = (alive >> c) & 1;
        uint64_t mask = __ballot(pred);
        uint32_t cnt = (uint32_t)__popcll(mask);
        if (pred) {
            uint32_t rank = (uint32_t)__popcll(mask & ((1ull << lane) - 1ull));
            if (rank < rem) win(c);
        }
        rem -= (cnt < rem) ? cnt : rem;
    }
}

// 3x3 SAME conv at cell i of the 28x28 grid stored in cnt.
__device__ __forceinline__ float conv_at(const uint32_t* cnt, const float* kl, int i) {
    int y  = i / HDIM;
    int xx = i - y * HDIM;
    float s = 0.0f;
    #pragma unroll
    for (int dy = 0; dy < 3; ++dy) {
        int yy = y + dy - 1;
        if (yy < 0 || yy >= HDIM) continue;
        #pragma unroll
        for (int dx = 0; dx < 3; ++dx) {
            int xc = xx + dx - 1;
            if (xc < 0 || xc >= HDIM) continue;
            s += kl[dy * 3 + dx] * (float)cnt[yy * HDIM + xc];
        }
    }
    return s;
}

__launch_bounds__(768, 1)
__global__ void mhv_kernel(const float* __restrict__ x,
                           const float* __restrict__ kern,
                           float* __restrict__ out,
                           int select_num) {
    const int b    = blockIdx.x;
    const int tid  = threadIdx.x;
    const int w    = tid >> 6;
    const int lane = tid & 63;

    __shared__ uint32_t cnt[PN];
    __shared__ float    convf[PN];
    __shared__ uint32_t hist[NH][NBIN];
    __shared__ uint32_t wout[64];
    __shared__ int      ticket;

    // ---- Issue ALL global loads first: their HBM latency hides under the
    // ---- LDS zeroing + barrier (neither depends on them).
    const size_t base = ((size_t)(b * NH + w) * SEQ) * SEQ + 1;  // x[b,h,0,1]
    float xv[NCHUNK];
    #pragma unroll
    for (int c = 0; c < NCHUNK; ++c) {
        int idx = c * 64 + lane;
        xv[c] = (idx < PN) ? x[base + idx] : 0.0f;
    }
    float kl[9];
    #pragma unroll
    for (int j = 0; j < 9; ++j) kl[j] = kern[j];

    for (int i = tid; i < PN; i += 768) cnt[i] = 0;
    if (tid == 0) ticket = 0;
    __syncthreads();

    // ---- Phase A: per-head (wave == head) top-24 vote -----------------------
    {
        uint32_t key[NCHUNK];
        #pragma unroll
        for (int c = 0; c < NCHUNK; ++c)
            key[c] = mono_key(xv[c]);               // pads (0.0f) < T0
        const uint32_t T0 = mono_key(1.5f);        // survivor threshold
        const uint32_t HI = mono_key(6.0f);        // renorm-shift overflow guard
        uint32_t pred = 0;
        uint32_t total = 0;
        uint64_t anyHi = 0;
        #pragma unroll
        for (int c = 0; c < NCHUNK; ++c) {
            int pv = key[c] >= T0;
            if (pv) pred |= 1u << c;
            total += (uint32_t)__popcll(__ballot(pv));
            anyHi |= __ballot(key[c] >= HI);
        }
        const uint32_t alivefull = (lane < (PN - 12 * 64)) ? 0x1FFFu : 0x0FFFu;
        uint32_t alive = (total >= VOTE) ? (pred & alivefull) : alivefull;
        if ((total >= VOTE) && anyHi == 0) {
            // survivors all in [1.5, 6.0): renormalize for digit entropy
            #pragma unroll
            for (int c = 0; c < NCHUNK; ++c) key[c] = (key[c] - T0) << 8;
        }
        wave_select<28>(key, alive, VOTE, hist[w], lane,
            [&](int c) { atomicAdd(&cnt[c * 64 + lane], 1u); });
    }
    __syncthreads();   // all votes in cnt

    // ---- Phase B: distributed conv. Wave w -> chunk w; wave 11 also chunk 12.
    const int i0 = w * 64 + lane;                  // always < 768
    float cv0 = conv_at(cnt, kl, i0);
    convf[i0] = cv0;
    float cv1 = 0.0f;
    if (w == 11 && lane < (PN - 768)) {            // chunk 12 (16 cells)
        cv1 = conv_at(cnt, kl, 768 + lane);
        convf[768 + lane] = cv1;
    }
    __syncthreads();   // convf complete (LDS-only drain; no global stores yet)

    // ---- Phase C: wave 0 selects; all waves store out1 from registers -------
    float* out1 = out + BATCH * select_num + (size_t)b * PN;
    out1[i0] = cv0;                                // issue store, don't wait
    if (w == 11 && lane < (PN - 768)) out1[768 + lane] = cv1;

    if (w == 0) {
        uint32_t v[NCHUNK];
        #pragma unroll
        for (int c = 0; c < NCHUNK; ++c) {
            int i = c * 64 + lane;
            v[c] = (i < PN) ? (uint32_t)(int)convf[i] : 0u;  // exact small ints
        }
        // wave max
        uint32_t m = v[0];
        #pragma unroll
        for (int c = 1; c < NCHUNK; ++c) m = (v[c] > m) ? v[c] : m;
        #pragma unroll
        for (int off = 1; off < 64; off <<= 1) {
            uint32_t t = __shfl_xor(m, off, 64);
            m = (t > m) ? t : m;
        }
        // 5 probe thresholds counted in ONE pass (packed per-lane counters)
        const uint32_t sn = (uint32_t)select_num;
        const uint32_t valid = (lane < (PN - 12 * 64)) ? 0x1FFFu : 0x0FFFu;
        const uint32_t T1 = (m + 1) >> 1, T2 = (m + 1) >> 2,
                       T3 = (m + 1) >> 3, T4 = (m + 1) >> 4, T5 = 1;
        uint32_t pa = 0, pb = 0, pc5 = 0;   // pa: c1|c2<<16, pb: c3|c4<<16
        #pragma unroll
        for (int c = 0; c < NCHUNK; ++c) {
            if ((valid >> c) & 1) {
                uint32_t k = v[c];
                pa += (k >= T1 ? 1u : 0u) | (k >= T2 ? 0x10000u : 0u);
                pb += (k >= T3 ? 1u : 0u) | (k >= T4 ? 0x10000u : 0u);
                pc5 += (k >= T5) ? 1u : 0u;
            }
        }
        #pragma unroll
        for (int off = 1; off < 64; off <<= 1) {
            pa += __shfl_xor(pa, off, 64);
            pb += __shfl_xor(pb, off, 64);
            pc5 += __shfl_xor(pc5, off, 64);
        }
        uint32_t c1 = pa & 0xFFFFu, c2 = pa >> 16;
        uint32_t c3 = pb & 0xFFFFu, c4 = pb >> 16;
        uint32_t T;
        if      (c1 >= sn) T = T1;
        else if (c2 >= sn) T = T2;
        else if (c3 >= sn) T = T3;
        else if (c4 >= sn) T = T4;
        else if (pc5 >= sn) T = T5;
        else               T = 0;           // safety (never expected)
        uint32_t alive = 0;
        #pragma unroll
        for (int c = 0; c < NCHUNK; ++c)
            if (((valid >> c) & 1) && v[c] >= T) alive |= 1u << c;
        // clz-normalize so radix digits carry the top significant bits
        const int lz = __clz((int)(m | 1u));
        uint32_t key[NCHUNK];
        #pragma unroll
        for (int c = 0; c < NCHUNK; ++c) key[c] = v[c] << lz;
        wave_select<28>(key, alive, sn, hist[0], lane,
            [&](int c) {
                int t = atomicAdd(&ticket, 1);
                wout[t] = (v[c] << 10) |
                          (1023u - (uint32_t)(c * 64 + lane));
            });
        __threadfence_block();
        if (lane < select_num) {
            uint32_t pk = wout[lane];
            int rank = 0;
            for (int m2 = 0; m2 < select_num; ++m2) rank += (wout[m2] > pk) ? 1 : 0;
            int idx = 1023 - (int)(pk & 1023u);
            out[(size_t)b * select_num + rank] = (float)(idx + 1);
        }
    }
}

extern "C" void kernel_launch(void* const* d_in, const int* in_sizes, int n_in,
                              void* d_out, int out_size, void* d_ws, size_t ws_size,
                              hipStream_t stream) {
    (void)in_sizes; (void)n_in; (void)d_ws; (void)ws_size;
    const float* x    = (const float*)d_in[0];
    const float* kern = (const float*)d_in[1];
    int select_num = (out_size - BATCH * PN) / BATCH;   // = 24
    mhv_kernel<<<dim3(BATCH), dim3(768), 0, stream>>>(x, kern, (float*)d_out, select_num);
}

// Round 8
// 18.612 us; speedup vs baseline: 1.2442x; 1.2442x over previous
//
#include <hip/hip_runtime.h>
#include <stdint.h>

#define BATCH 32
#define NH 12
#define SEQ 785
#define PN 784        // patch_num
#define HDIM 28       // 28*28 == 784
#define VOTE 24       // VOTE_PERHEAD
#define NCHUNK 13     // ceil(784/64)
#define NBIN 128

// Monotonic float -> uint32: k(a) > k(b) iff a > b (finite floats).
__device__ __forceinline__ uint32_t mono_key(float f) {
    uint32_t u = __float_as_uint(f);
    return (u & 0x80000000u) ? ~u : (u | 0x80000000u);
}

// Wave-parallel radix top-r select over 32-bit VALUE keys (desc); ties broken
// by ascending element index (element (c,lane) has index c*64+lane).
// key[c] valid iff bit c of `alive`. Calls win(c) exactly r times.
// 7-bit digits from SHIFT0 down to 0; after the last pass any remaining
// alive elements share one exact key -> ballot rank-select by index.
template <int SHIFT0, typename WinF>
__device__ __forceinline__ void wave_select(const uint32_t* key, uint32_t alive,
                                            uint32_t r, uint32_t* histRow,
                                            int lane, WinF&& win) {
    static_assert(SHIFT0 % 7 == 0, "SHIFT0 must be a multiple of 7");
    constexpr int NPASS = SHIFT0 / 7 + 1;
    #pragma unroll 1
    for (int p = 0; p < NPASS; ++p) {
        const int shift = SHIFT0 - 7 * p;
        histRow[2 * lane]     = 0;
        histRow[2 * lane + 1] = 0;
        __threadfence_block();
        #pragma unroll
        for (int c = 0; c < NCHUNK; ++c)
            if (alive & (1u << c))
                atomicAdd(&histRow[(key[c] >> shift) & (NBIN - 1)], 1u);
        __threadfence_block();
        uint32_t h0 = histRow[2 * lane];
        uint32_t h1 = histRow[2 * lane + 1];
        uint32_t x = h0 + h1;
        #pragma unroll
        for (int off = 1; off < 64; off <<= 1) {
            uint32_t t = __shfl_down(x, off, 64);
            if (lane + off < 64) x += t;
        }
        uint32_t tail = x - h0 - h1;          // count of digits >= 2*lane+2
        uint32_t Bc = 0, rc = 0, cc = 0;
        int found = 0;
        if (tail < r && r <= tail + h1) {
            Bc = 2 * lane + 1; rc = r - tail; cc = h1; found = 1;
        } else if (tail + h1 < r && r <= tail + h1 + h0) {
            Bc = 2 * lane; rc = r - tail - h1; cc = h0; found = 1;
        }
        uint64_t fm = __ballot(found);         // exactly one lane sets found
        int src = (int)(__ffsll((unsigned long long)fm) - 1);
        uint32_t B    = __shfl(Bc, src, 64);
        uint32_t rnew = __shfl(rc, src, 64);
        uint32_t cb   = __shfl(cc, src, 64);
        #pragma unroll
        for (int c = 0; c < NCHUNK; ++c) {
            if (alive & (1u << c)) {
                uint32_t bin = (key[c] >> shift) & (NBIN - 1);
                if (bin > B)      { win(c); alive &= ~(1u << c); }
                else if (bin < B) { alive &= ~(1u << c); }
            }
        }
        r = rnew;
        if (cb == rnew) {                      // threshold bin fully wins
            #pragma unroll
            for (int c = 0; c < NCHUNK; ++c)
                if (alive & (1u << c)) win(c);
            return;
        }
    }
    // Exact-value tie: take the r smallest indices among alive.
    uint32_t rem = r;
    #pragma unroll 1
    for (int c = 0; c < NCHUNK && rem; ++c) {
        int pred = (alive >> c) & 1;
        uint64_t mask = __ballot(pred);
        uint32_t cnt = (uint32_t)__popcll(mask);
        if (pred) {
            uint32_t rank = (uint32_t)__popcll(mask & ((1ull << lane) - 1ull));
            if (rank < rem) win(c);
        }
        rem -= (cnt < rem) ? cnt : rem;
    }
}

// 3x3 SAME conv at cell i of the 28x28 grid stored in cnt.
__device__ __forceinline__ float conv_at(const uint32_t* cnt, const float* kl, int i) {
    int y  = i / HDIM;
    int xx = i - y * HDIM;
    float s = 0.0f;
    #pragma unroll
    for (int dy = 0; dy < 3; ++dy) {
        int yy = y + dy - 1;
        if (yy < 0 || yy >= HDIM) continue;
        #pragma unroll
        for (int dx = 0; dx < 3; ++dx) {
            int xc = xx + dx - 1;
            if (xc < 0 || xc >= HDIM) continue;
            s += kl[dy * 3 + dx] * (float)cnt[yy * HDIM + xc];
        }
    }
    return s;
}

__launch_bounds__(768, 1)
__global__ void mhv_kernel(const float* __restrict__ x,
                           const float* __restrict__ kern,
                           float* __restrict__ out,
                           int select_num) {
    const int b    = blockIdx.x;
    const int tid  = threadIdx.x;
    const int w    = tid >> 6;
    const int lane = tid & 63;

    __shared__ uint32_t cnt[PN];
    __shared__ float    convf[PN];
    __shared__ uint32_t hist[NH][NBIN];
    __shared__ uint32_t wout[64];
    __shared__ int      ticket;

    for (int i = tid; i < PN; i += 768) cnt[i] = 0;
    if (tid == 0) ticket = 0;
    __syncthreads();

    // Prefetch kernel weights (latency hides under Phase A).
    float kl[9];
    #pragma unroll
    for (int j = 0; j < 9; ++j) kl[j] = kern[j];

    // ---- Phase A: per-head (wave == head) top-24 vote -----------------------
    {
        const size_t base = ((size_t)(b * NH + w) * SEQ) * SEQ + 1;  // x[b,h,0,1]
        uint32_t key[NCHUNK];
        #pragma unroll
        for (int c = 0; c < NCHUNK; ++c) {
            int idx = c * 64 + lane;
            key[c] = (idx < PN) ? mono_key(x[base + idx]) : 0u;   // pads -> 0 (< T0)
        }
        const uint32_t T0 = mono_key(1.5f);        // survivor threshold
        const uint32_t HI = mono_key(6.0f);        // renorm-shift overflow guard
        uint32_t pred = 0;
        uint32_t total = 0;
        uint64_t anyHi = 0;
        #pragma unroll
        for (int c = 0; c < NCHUNK; ++c) {
            int pv = key[c] >= T0;
            if (pv) pred |= 1u << c;
            total += (uint32_t)__popcll(__ballot(pv));
            anyHi |= __ballot(key[c] >= HI);
        }
        const uint32_t alivefull = (lane < (PN - 12 * 64)) ? 0x1FFFu : 0x0FFFu;
        uint32_t alive = (total >= VOTE) ? pred : alivefull;
        if ((total >= VOTE) && anyHi == 0) {
            // survivors all in [1.5, 6.0): renormalize for digit entropy
            #pragma unroll
            for (int c = 0; c < NCHUNK; ++c) key[c] = (key[c] - T0) << 8;
        }
        wave_select<28>(key, alive, VOTE, hist[w], lane,
            [&](int c) { atomicAdd(&cnt[c * 64 + lane], 1u); });
    }
    __syncthreads();   // all votes in cnt

    // ---- Phase B: distributed conv. Wave w -> chunk w; wave 11 also chunk 12.
    const int i0 = w * 64 + lane;                  // always < 768
    float cv0 = conv_at(cnt, kl, i0);
    convf[i0] = cv0;
    float cv1 = 0.0f;
    if (w == 11 && lane < (PN - 768)) {            // chunk 12 (16 cells)
        cv1 = conv_at(cnt, kl, 768 + lane);
        convf[768 + lane] = cv1;
    }
    __syncthreads();   // convf complete (LDS-only drain; no global stores yet)

    // ---- Phase C: wave 0 selects; all waves store out1 from registers -------
    float* out1 = out + BATCH * select_num + (size_t)b * PN;
    out1[i0] = cv0;                                // issue store, don't wait
    if (w == 11 && lane < (PN - 768)) out1[768 + lane] = cv1;

    if (w == 0) {
        uint32_t key[NCHUNK];
        #pragma unroll
        for (int c = 0; c < NCHUNK; ++c) {
            int i = c * 64 + lane;
            key[c] = (i < PN) ? (uint32_t)(int)convf[i] : 0u;  // exact small ints
        }
        // adaptive threshold: halve from wave-max until >= select_num survive
        uint32_t m = key[0];
        #pragma unroll
        for (int c = 1; c < NCHUNK; ++c) m = (key[c] > m) ? key[c] : m;
        #pragma unroll
        for (int off = 1; off < 64; off <<= 1) {
            uint32_t t = __shfl_xor(m, off, 64);
            m = (t > m) ? t : m;
        }
        const uint32_t valid = (lane < (PN - 12 * 64)) ? 0x1FFFu : 0x0FFFu;
        uint32_t T = m;
        uint32_t alive = 0;
        for (;;) {
            uint32_t total = 0;
            uint32_t pr = 0;
            #pragma unroll
            for (int c = 0; c < NCHUNK; ++c) {
                int pv = ((valid >> c) & 1) && (key[c] >= T);
                if (pv) pr |= 1u << c;
                total += (uint32_t)__popcll(__ballot(pv));
            }
            if (total >= (uint32_t)select_num || T == 0) { alive = pr; break; }
            T >>= 1;
        }
        // conv <= 288*16 = 4608 < 2^14 -> 2 radix passes from shift 7
        wave_select<7>(key, alive, (uint32_t)select_num, hist[0], lane,
            [&](int c) {
                int t = atomicAdd(&ticket, 1);
                wout[t] = (key[c] << 10) |
                          (1023u - (uint32_t)(c * 64 + lane));
            });
        __threadfence_block();
        if (lane < select_num) {
            uint32_t pk = wout[lane];
            int rank = 0;
            for (int m2 = 0; m2 < select_num; ++m2) rank += (wout[m2] > pk) ? 1 : 0;
            int idx = 1023 - (int)(pk & 1023u);
            out[(size_t)b * select_num + rank] = (float)(idx + 1);
        }
    }
}

extern "C" void kernel_launch(void* const* d_in, const int* in_sizes, int n_in,
                              void* d_out, int out_size, void* d_ws, size_t ws_size,
                              hipStream_t stream) {
    (void)in_sizes; (void)n_in; (void)d_ws; (void)ws_size;
    const float* x    = (const float*)d_in[0];
    const float* kern = (const float*)d_in[1];
    int select_num = (out_size - BATCH * PN) / BATCH;   // = 24
    mhv_kernel<<<dim3(BATCH), dim3(768), 0, stream>>>(x, kern, (float*)d_out, select_num);
}